// Round 4
// baseline (543.984 us; speedup 1.0000x reference)
//
#include <hip/hip_runtime.h>
#include <hip/hip_bf16.h>

#define BATCH 32
#define CIN   256
#define COUT  256
#define Hd    56
#define Wd    56
#define HW    (Hd*Wd)

typedef __attribute__((ext_vector_type(8))) short bf16x8;
typedef __attribute__((ext_vector_type(4))) float f32x4;

typedef const __attribute__((address_space(1))) void* gas1_t;
typedef __attribute__((address_space(3))) void* las3_t;

__device__ __forceinline__ unsigned short f2bf_rne(float f) {
    unsigned u = __builtin_bit_cast(unsigned, f);
    u += 0x7fffu + ((u >> 16) & 1u);
    return (unsigned short)(u >> 16);
}

// ---------------------------------------------------------------------------
// Weight prep: Wc[np][kp] center taps, Wg[np][t][j] off-center taps, bsum[np].
// permutation: np = (n%4)*64 + n/4 ; kp likewise for inputs.
// ---------------------------------------------------------------------------
__global__ void hetconv_prep(const float* __restrict__ W, const float* __restrict__ b,
                             unsigned short* __restrict__ Wc,
                             unsigned short* __restrict__ Wg,
                             float* __restrict__ bsum) {
    const int np = blockIdx.x;
    const int lane = threadIdx.x;
    const int r = np >> 6;
    const int n = ((np & 63) << 2) | r;

    float s = 0.f;
    for (int i = lane; i < CIN; i += 64) s += b[n * CIN + i];
    #pragma unroll
    for (int off = 32; off > 0; off >>= 1) s += __shfl_down(s, off, 64);
    if (lane == 0) bsum[np] = s;

    for (int kp = lane; kp < CIN; kp += 64) {
        int i = ((kp & 63) << 2) | (kp >> 6);
        Wc[np * CIN + kp] = f2bf_rne(W[(n * CIN + i) * 9 + 4]);
    }
    for (int u = lane; u < 8 * 64; u += 64) {
        int t = u >> 6, j = u & 63;
        int tap = t + (t >= 4);
        int i = (j << 2) | r;
        Wg[np * 512 + u] = f2bf_rne(W[(n * CIN + i) * 9 + tap]);
    }
}

// ---------------------------------------------------------------------------
// x convert: xb[b][pass4][row 58 (rows 0,57 zero)][col 64 (56-63 zero)]
// [64 ch bf16, octet-XOR-swizzled by col&7].  pass == input residue.
// Octet g of pass p holds permuted channels kp = p*64 + g*8 + e.
// ---------------------------------------------------------------------------
__global__ __launch_bounds__(512) void hetconv_xconv(const float* __restrict__ x,
                                                     unsigned short* __restrict__ xb) {
    const int bid = blockIdx.x;
    const int b  = bid / 58;
    const int pr = bid % 58;
    const int tid = threadIdx.x;
    const int col = tid & 63;
    const int wid = tid >> 6;
    const int grow = pr - 1;
    const bool ok = (grow >= 0) && (grow < Hd) && (col < Wd);
    const float* xp = x + (size_t)b * CIN * HW + (size_t)grow * Wd + col;

    #pragma unroll
    for (int rd = 0; rd < 4; ++rd) {
        int octG = rd * 8 + wid;          // [0,32)
        int pass = octG >> 3;             // residue
        int g    = octG & 7;
        bf16x8 pk;
        #pragma unroll
        for (int e = 0; e < 8; ++e) {
            int j = g * 8 + e;            // index within group
            int ic = (j << 2) | pass;     // global channel
            float f = ok ? xp[(size_t)ic * HW] : 0.f;
            pk[e] = (short)f2bf_rne(f);
        }
        size_t dst = ((size_t)(b * 4 + pass) * 58 + pr) * 4096
                   + col * 64 + ((g ^ (col & 7)) * 8);
        *reinterpret_cast<bf16x8*>(xb + dst) = pk;
    }
}

// ---------------------------------------------------------------------------
// Main: 512 blocks = 32 b x 16 rowgroups (12x2 + 4x1 two-row tiles).
// 8 waves = (row h) x (out-residue r). Pass p stages 64 ch (= residue p).
// Per step: dense A-frag loads FIRST, then next-slab prefetch (6 non-grouped
// waves), dense MFMA (waits vmcnt(chunks) only), grouped MFMA for waves r==p
// (no outstanding prefetch on those waves), vmcnt(0)+barrier once per step.
// Tile epilogue: acc -> dead LDS buffer -> coalesced float4 stores.
// ---------------------------------------------------------------------------
__global__ __launch_bounds__(512, 4) void hetconv_main(const unsigned short* __restrict__ xb,
                             const unsigned short* __restrict__ Wc,
                             const unsigned short* __restrict__ Wg,
                             const float* __restrict__ bsum,
                             float* __restrict__ y) {
    __shared__ unsigned short xs[2][16384];   // 2 x 32 KB

    const int bid = blockIdx.x;
    const int b   = bid >> 4;
    const int rg  = bid & 15;
    const int tr0 = (rg < 12) ? rg * 4 : 48 + (rg - 12) * 2;
    const int T   = (rg < 12) ? 2 : 1;
    const int NS  = T * 4;

    const int tid  = threadIdx.x;
    const int lane = tid & 63;
    const int wid  = tid >> 6;
    const int h = wid & 1;
    const int r = wid >> 1;
    const int l15 = lane & 15;
    const int l4  = lane >> 4;

    f32x4 acc[4][4];
    #pragma unroll
    for (int i = 0; i < 4; ++i)
        #pragma unroll
        for (int j = 0; j < 4; ++j) acc[i][j] = f32x4{0.f, 0.f, 0.f, 0.f};

    // prologue: stage (tile0, pass0), drain once
    {
        const unsigned short* slab = xb + ((size_t)(b * 4 + 0) * 58 + tr0) * 4096;
        #pragma unroll
        for (int c0 = 0; c0 < 4; ++c0) {
            int c = c0 * 8 + wid;
            __builtin_amdgcn_global_load_lds(
                (gas1_t)(slab + c * 512 + lane * 8),
                (las3_t)(&xs[0][c * 512]), 16, 0, 0);
        }
        asm volatile("s_waitcnt vmcnt(0)" ::: "memory");
        __builtin_amdgcn_s_barrier();
    }

    for (int st = 0; st < NS; ++st) {
        const int t  = st >> 2;
        const int p  = st & 3;
        const int tr = tr0 + t * 2;
        const unsigned short* bufC = xs[st & 1];
        unsigned short*       bufN = xs[(st & 1) ^ 1];
        const bool grouped = (r == p);

        // ---- dense A-frags for this pass, issued BEFORE prefetch ----
        bf16x8 af[2][4];
        #pragma unroll
        for (int ks = 0; ks < 2; ++ks)
            #pragma unroll
            for (int mf = 0; mf < 4; ++mf) {
                int m = r * 64 + mf * 16 + l15;
                af[ks][mf] = *reinterpret_cast<const bf16x8*>(
                    Wc + (size_t)m * 256 + p * 64 + ks * 32 + l4 * 8);
            }
        __builtin_amdgcn_sched_barrier(0);

        // ---- prefetch next slab (6 non-grouped waves only) ----
        if (st + 1 < NS && !grouped) {
            int u = wid - (wid > 2 * p + 1 ? 2 : 0);     // [0,6)
            int p2 = (st + 1) & 3;
            int tr2 = tr0 + ((st + 1) >> 2) * 2;
            const unsigned short* slab = xb + ((size_t)(b * 4 + p2) * 58 + tr2) * 4096;
            for (int c = u; c < 32; c += 6)
                __builtin_amdgcn_global_load_lds(
                    (gas1_t)(slab + c * 512 + lane * 8),
                    (las3_t)(bufN + c * 512), 16, 0, 0);
        }

        // ---- dense center-tap GEMM: 2 K-steps of 32 channels ----
        {
            const int srow = (h + 1) * 64;
            #pragma unroll
            for (int ks = 0; ks < 2; ++ks) {
                #pragma unroll
                for (int nf = 0; nf < 4; ++nf) {
                    int s = srow + nf * 16 + l15;
                    int o = ks * 4 + l4;
                    int addr = s * 128 + ((o ^ (s & 7)) << 4);
                    bf16x8 bb = *reinterpret_cast<const bf16x8*>(
                        reinterpret_cast<const char*>(bufC) + addr);
                    #pragma unroll
                    for (int mf = 0; mf < 4; ++mf)
                        acc[mf][nf] = __builtin_amdgcn_mfma_f32_16x16x32_bf16(
                            af[ks][mf], bb, acc[mf][nf], 0, 0, 0);
                }
            }
        }

        // ---- grouped off-center taps (waves r == p; no prefetch queued) ----
        if (grouped) {
            #pragma unroll
            for (int t8 = 0; t8 < 8; ++t8) {
                const int tap = t8 + (t8 >= 4);
                const int dy = tap / 3 - 1;
                const int dx = tap % 3 - 1;
                const int srow = (h + 1 + dy) * 64;
                #pragma unroll
                for (int ks2 = 0; ks2 < 2; ++ks2) {
                    bf16x8 a[4];
                    #pragma unroll
                    for (int mf = 0; mf < 4; ++mf) {
                        int m = r * 64 + mf * 16 + l15;
                        a[mf] = *reinterpret_cast<const bf16x8*>(
                            Wg + ((size_t)m * 8 + t8) * 64 + ks2 * 32 + l4 * 8);
                    }
                    #pragma unroll
                    for (int nf = 0; nf < 4; ++nf) {
                        int c2 = nf * 16 + l15 + dx;
                        c2 = ((unsigned)c2 < 64u) ? c2 : 56;   // col 56 is zero pad
                        int s = srow + c2;
                        int o = ks2 * 4 + l4;
                        int addr = s * 128 + ((o ^ (s & 7)) << 4);
                        bf16x8 bb = *reinterpret_cast<const bf16x8*>(
                            reinterpret_cast<const char*>(bufC) + addr);
                        #pragma unroll
                        for (int mf = 0; mf < 4; ++mf)
                            acc[mf][nf] = __builtin_amdgcn_mfma_f32_16x16x32_bf16(
                                a[mf], bb, acc[mf][nf], 0, 0, 0);
                    }
                }
            }
        }

        asm volatile("s_waitcnt vmcnt(0)" ::: "memory");
        __builtin_amdgcn_s_barrier();

        // ---- tile epilogue (after pass 3): staged coalesced stores ----
        if (p == 3) {
            float* lf = reinterpret_cast<float*>(const_cast<unsigned short*>(bufC));
            #pragma unroll
            for (int q = 0; q < 4; ++q) {
                if (r == q) {
                    #pragma unroll
                    for (int mf = 0; mf < 4; ++mf) {
                        #pragma unroll
                        for (int j = 0; j < 4; ++j) {
                            int npl = mf * 16 + l4 * 4 + j;
                            float bias = bsum[q * 64 + npl];
                            #pragma unroll
                            for (int nf = 0; nf < 4; ++nf) {
                                int col = nf * 16 + l15;
                                if (col < Wd)
                                    lf[npl * 116 + h * 56 + col] = acc[mf][nf][j] + bias;
                            }
                            #pragma unroll
                            for (int nf = 0; nf < 4; ++nf) acc[mf][nf][j] = 0.f;
                        }
                    }
                }
                __syncthreads();
                #pragma unroll
                for (int it = 0; it < 4; ++it) {
                    int v = it * 512 + tid;           // 64 npl x 28 float4
                    if (v < 1792) {
                        int npl = v / 28;
                        int f   = v % 28;
                        int row = (f >= 14) ? 1 : 0;
                        int c4  = f - row * 14;
                        int n = (npl << 2) | q;
                        f32x4 val = *reinterpret_cast<const f32x4*>(lf + npl * 116 + f * 4);
                        *reinterpret_cast<f32x4*>(
                            y + (((size_t)b * COUT + n) * Hd + (tr + row)) * Wd + c4 * 4) = val;
                    }
                }
                __syncthreads();
            }
        }
    }
}

extern "C" void kernel_launch(void* const* d_in, const int* in_sizes, int n_in,
                              void* d_out, int out_size, void* d_ws, size_t ws_size,
                              hipStream_t stream) {
    const float* x = (const float*)d_in[0];
    const float* W = (const float*)d_in[1];
    const float* b = (const float*)d_in[2];
    float* y = (float*)d_out;

    unsigned short* Wc   = (unsigned short*)d_ws;                        // 131072 B
    unsigned short* Wg   = (unsigned short*)((char*)d_ws + 131072);      // 262144 B
    float*          bsum = (float*)((char*)d_ws + 393216);               // 1024 B
    unsigned short* xb   = (unsigned short*)((char*)d_ws + 394240);      // 60,817,408 B

    hipLaunchKernelGGL(hetconv_prep,  dim3(256),        dim3(64),  0, stream, W, b, Wc, Wg, bsum);
    hipLaunchKernelGGL(hetconv_xconv, dim3(BATCH * 58), dim3(512), 0, stream, x, xb);
    hipLaunchKernelGGL(hetconv_main,  dim3(512),        dim3(512), 0, stream, xb, Wc, Wg, bsum, y);
}

// Round 5
// 345.937 us; speedup vs baseline: 1.5725x; 1.5725x over previous
//
#include <hip/hip_runtime.h>
#include <hip/hip_bf16.h>

#define BATCH 32
#define CIN   256
#define COUT  256
#define Hd    56
#define Wd    56
#define HW    (Hd*Wd)

typedef __attribute__((ext_vector_type(8))) short bf16x8;
typedef __attribute__((ext_vector_type(4))) float f32x4;

typedef const __attribute__((address_space(1))) void* gas1_t;
typedef __attribute__((address_space(3))) void* las3_t;

__device__ __forceinline__ unsigned short f2bf_rne(float f) {
    unsigned u = __builtin_bit_cast(unsigned, f);
    u += 0x7fffu + ((u >> 16) & 1u);
    return (unsigned short)(u >> 16);
}

// ---------------------------------------------------------------------------
// Weight prep: Wc[np][kp] center taps, Wg[np][t][j] off-center taps, bsum[np].
// permutation: np = (n%4)*64 + n/4 ; kp likewise for inputs.
// ---------------------------------------------------------------------------
__global__ void hetconv_prep(const float* __restrict__ W, const float* __restrict__ b,
                             unsigned short* __restrict__ Wc,
                             unsigned short* __restrict__ Wg,
                             float* __restrict__ bsum) {
    const int np = blockIdx.x;
    const int lane = threadIdx.x;
    const int r = np >> 6;
    const int n = ((np & 63) << 2) | r;

    float s = 0.f;
    for (int i = lane; i < CIN; i += 64) s += b[n * CIN + i];
    #pragma unroll
    for (int off = 32; off > 0; off >>= 1) s += __shfl_down(s, off, 64);
    if (lane == 0) bsum[np] = s;

    for (int kp = lane; kp < CIN; kp += 64) {
        int i = ((kp & 63) << 2) | (kp >> 6);
        Wc[np * CIN + kp] = f2bf_rne(W[(n * CIN + i) * 9 + 4]);
    }
    for (int u = lane; u < 8 * 64; u += 64) {
        int t = u >> 6, j = u & 63;
        int tap = t + (t >= 4);
        int i = (j << 2) | r;
        Wg[np * 512 + u] = f2bf_rne(W[(n * CIN + i) * 9 + tap]);
    }
}

// ---------------------------------------------------------------------------
// x convert (R2 layout): xb[b][pass2][row 58 (rows 0,57 zero)][col 64 (56-63
// zero)][128 ch bf16, octet-XOR-swizzled by col&7].
// ---------------------------------------------------------------------------
__global__ __launch_bounds__(512) void hetconv_xconv(const float* __restrict__ x,
                                                     unsigned short* __restrict__ xb) {
    const int bid = blockIdx.x;
    const int b  = bid / 58;
    const int pr = bid % 58;
    const int tid = threadIdx.x;
    const int col = tid & 63;
    const int wid = tid >> 6;
    const int grow = pr - 1;
    const bool ok = (grow >= 0) && (grow < Hd) && (col < Wd);
    const float* xp = x + (size_t)b * CIN * HW + (size_t)grow * Wd + col;

    #pragma unroll
    for (int rd = 0; rd < 4; ++rd) {
        int octG = rd * 8 + wid;          // [0,32)
        int pass = octG >> 4;
        int g    = octG & 15;
        bf16x8 pk;
        #pragma unroll
        for (int e = 0; e < 8; ++e) {
            int kp = pass * 128 + g * 8 + e;
            int ic = ((kp & 63) << 2) | (kp >> 6);
            float f = ok ? xp[(size_t)ic * HW] : 0.f;
            pk[e] = (short)f2bf_rne(f);
        }
        size_t dst = ((size_t)(b * 2 + pass) * 58 + pr) * 8192
                   + col * 128 + ((g ^ (col & 7)) * 8);
        *reinterpret_cast<bf16x8*>(xb + dst) = pk;
    }
}

// ---------------------------------------------------------------------------
// Stage one 64 KB slab (4 padded rows x 64 cols x 128 ch) -> LDS.
// All 8 waves, 8 chunks each, compile-time counts.
// ---------------------------------------------------------------------------
__device__ __forceinline__ void stage_slab(const unsigned short* __restrict__ xb,
                                           unsigned short* lds_dst,
                                           int b, int tr, int p, int wid, int lane) {
    const unsigned short* slab = xb + ((size_t)((b * 2 + p) * 58 + tr)) * 8192;
    #pragma unroll
    for (int rd = 0; rd < 8; ++rd) {
        int vbase = rd * 512 + wid * 64;           // 16B units, wave-uniform
        __builtin_amdgcn_global_load_lds(
            (gas1_t)(slab + (size_t)(vbase + lane) * 8),
            (las3_t)(lds_dst + vbase * 8), 16, 0, 0);
    }
}

// ---------------------------------------------------------------------------
// Main: 256 persistent blocks = 32 b x 8 rowgroups (4,4,4,4,3,3,3,3 tiles).
// 8 waves = (row h) x (out-residue r). Per step (tile t, pass p of 128 ch):
//   [all weight A-frags issued]  sched_barrier  [stage next slab]
//   [dense MFMA (waits vmcnt(8), stage stays in flight)]
//   [grouped MFMA, waves r>>1==p, Wg depth-1 register prefetch]
//   vmcnt(0) + barrier.   Tile end: LDS-staged coalesced float4 epilogue.
// ---------------------------------------------------------------------------
__global__ __launch_bounds__(512, 2) void hetconv_main(const unsigned short* __restrict__ xb,
                             const unsigned short* __restrict__ Wc,
                             const unsigned short* __restrict__ Wg,
                             const float* __restrict__ bsum,
                             float* __restrict__ y) {
    __shared__ unsigned short xs[2][32768];   // 2 x 64 KB

    const int bid = blockIdx.x;
    const int b   = bid >> 3;
    const int rg  = bid & 7;
    const int tr0 = (rg < 4) ? rg * 8 : 32 + (rg - 4) * 6;   // first output row
    const int T   = (rg < 4) ? 4 : 3;                        // 2-row tiles
    const int NS  = T * 2;

    const int tid  = threadIdx.x;
    const int lane = tid & 63;
    const int wid  = tid >> 6;
    const int h = wid & 1;
    const int r = wid >> 1;
    const int l15 = lane & 15;
    const int l4  = lane >> 4;

    f32x4 acc[4][4];
    #pragma unroll
    for (int i = 0; i < 4; ++i)
        #pragma unroll
        for (int j = 0; j < 4; ++j) acc[i][j] = f32x4{0.f, 0.f, 0.f, 0.f};

    // prologue: stage (tile0, pass0), drain once
    stage_slab(xb, xs[0], b, tr0, 0, wid, lane);
    asm volatile("s_waitcnt vmcnt(0)" ::: "memory");
    __builtin_amdgcn_s_barrier();

    for (int st = 0; st < NS; ++st) {
        const int t  = st >> 1;
        const int p  = st & 1;
        const int tr = tr0 + t * 2;
        const unsigned short* bufC = xs[st & 1];
        unsigned short*       bufN = xs[(st & 1) ^ 1];
        const bool grouped = ((r >> 1) == p);
        const int cbase = (r & 1) * 64;

        // ---- ALL dense A-frags for this pass, issued BEFORE staging ----
        bf16x8 af[4][4];
        #pragma unroll
        for (int ks = 0; ks < 4; ++ks)
            #pragma unroll
            for (int mf = 0; mf < 4; ++mf) {
                int m = r * 64 + mf * 16 + l15;
                af[ks][mf] = *reinterpret_cast<const bf16x8*>(
                    Wc + (size_t)m * 256 + p * 128 + ks * 32 + l4 * 8);
            }
        // first grouped Wg pair, also before staging
        bf16x8 agA[4], agB[4];
        if (grouped) {
            #pragma unroll
            for (int mf = 0; mf < 4; ++mf) {
                int m = r * 64 + mf * 16 + l15;
                agA[mf] = *reinterpret_cast<const bf16x8*>(
                    Wg + ((size_t)m * 8 + 0) * 64 + 0 * 32 + l4 * 8);
            }
        }
        __builtin_amdgcn_sched_barrier(0);

        // ---- stage next slab (8 chunks/wave, compile-time count) ----
        if (st + 1 < NS)
            stage_slab(xb, bufN, b, tr0 + ((st + 1) >> 1) * 2, (st + 1) & 1, wid, lane);

        // ---- dense center-tap GEMM: 4 K-steps of 32 channels ----
        {
            const int srow = (h + 1) * 64;
            #pragma unroll
            for (int ks = 0; ks < 4; ++ks) {
                #pragma unroll
                for (int nf = 0; nf < 4; ++nf) {
                    int s = srow + nf * 16 + l15;
                    int o = ks * 4 + l4;
                    int addr = s * 256 + ((o ^ (s & 7)) << 4);
                    bf16x8 bb = *reinterpret_cast<const bf16x8*>(
                        reinterpret_cast<const char*>(bufC) + addr);
                    #pragma unroll
                    for (int mf = 0; mf < 4; ++mf)
                        acc[mf][nf] = __builtin_amdgcn_mfma_f32_16x16x32_bf16(
                            af[ks][mf], bb, acc[mf][nf], 0, 0, 0);
                }
            }
        }

        // ---- grouped off-center taps, depth-1 register prefetch ----
        if (grouped) {
            #pragma unroll
            for (int idx = 0; idx < 16; ++idx) {
                const int t8  = idx >> 1;
                const int ks2 = idx & 1;
                const int tap = t8 + (t8 >= 4);
                const int dy = tap / 3 - 1;
                const int dx = tap % 3 - 1;
                const int srow = (h + 1 + dy) * 64;
                // prefetch next pair into the other named buffer
                if (idx + 1 < 16) {
                    const int t8n  = (idx + 1) >> 1;
                    const int ks2n = (idx + 1) & 1;
                    if ((idx & 1) == 0) {
                        #pragma unroll
                        for (int mf = 0; mf < 4; ++mf) {
                            int m = r * 64 + mf * 16 + l15;
                            agB[mf] = *reinterpret_cast<const bf16x8*>(
                                Wg + ((size_t)m * 8 + t8n) * 64 + ks2n * 32 + l4 * 8);
                        }
                    } else {
                        #pragma unroll
                        for (int mf = 0; mf < 4; ++mf) {
                            int m = r * 64 + mf * 16 + l15;
                            agA[mf] = *reinterpret_cast<const bf16x8*>(
                                Wg + ((size_t)m * 8 + t8n) * 64 + ks2n * 32 + l4 * 8);
                        }
                    }
                }
                #pragma unroll
                for (int nf = 0; nf < 4; ++nf) {
                    int c2 = nf * 16 + l15 + dx;
                    c2 = ((unsigned)c2 < 64u) ? c2 : 56;   // col 56 is zero pad
                    int s = srow + c2;
                    int o = ((cbase + ks2 * 32) >> 3) + l4;
                    int addr = s * 256 + ((o ^ (s & 7)) << 4);
                    bf16x8 bb = *reinterpret_cast<const bf16x8*>(
                        reinterpret_cast<const char*>(bufC) + addr);
                    #pragma unroll
                    for (int mf = 0; mf < 4; ++mf)
                        acc[mf][nf] = __builtin_amdgcn_mfma_f32_16x16x32_bf16(
                            ((idx & 1) == 0) ? agA[mf] : agB[mf], bb, acc[mf][nf], 0, 0, 0);
                }
            }
        }

        asm volatile("s_waitcnt vmcnt(0)" ::: "memory");
        __builtin_amdgcn_s_barrier();

        // ---- tile epilogue (after pass 1): staged coalesced stores ----
        if (p == 1) {
            float* lf = reinterpret_cast<float*>(const_cast<unsigned short*>(bufC));
            #pragma unroll
            for (int q = 0; q < 2; ++q) {
                if ((r >> 1) == q) {
                    #pragma unroll
                    for (int mf = 0; mf < 4; ++mf) {
                        #pragma unroll
                        for (int j = 0; j < 4; ++j) {
                            int chL = (r & 1) * 64 + mf * 16 + l4 * 4 + j;
                            float bias = bsum[q * 128 + chL];
                            #pragma unroll
                            for (int nf = 0; nf < 4; ++nf) {
                                int col = nf * 16 + l15;
                                if (col < Wd)
                                    lf[chL * 116 + h * 56 + col] = acc[mf][nf][j] + bias;
                            }
                            #pragma unroll
                            for (int nf = 0; nf < 4; ++nf) acc[mf][nf][j] = 0.f;
                        }
                    }
                }
                __syncthreads();
                #pragma unroll
                for (int it = 0; it < 7; ++it) {
                    int v = it * 512 + tid;            // 128 chL x 28 float4
                    int chL = v / 28;
                    int f   = v % 28;
                    int h2  = (f >= 14) ? 1 : 0;
                    int colS = (f - h2 * 14) * 4;
                    int n = ((chL & 63) << 2) | (q * 2 + (chL >> 6));
                    f32x4 val = *reinterpret_cast<const f32x4*>(lf + chL * 116 + f * 4);
                    *reinterpret_cast<f32x4*>(
                        y + (((size_t)b * COUT + n) * Hd + (tr + h2)) * Wd + colS) = val;
                }
                __syncthreads();
            }
        }
    }
}

extern "C" void kernel_launch(void* const* d_in, const int* in_sizes, int n_in,
                              void* d_out, int out_size, void* d_ws, size_t ws_size,
                              hipStream_t stream) {
    const float* x = (const float*)d_in[0];
    const float* W = (const float*)d_in[1];
    const float* b = (const float*)d_in[2];
    float* y = (float*)d_out;

    unsigned short* Wc   = (unsigned short*)d_ws;                        // 131072 B
    unsigned short* Wg   = (unsigned short*)((char*)d_ws + 131072);      // 262144 B
    float*          bsum = (float*)((char*)d_ws + 393216);               // 1024 B
    unsigned short* xb   = (unsigned short*)((char*)d_ws + 394240);      // 60,817,408 B

    hipLaunchKernelGGL(hetconv_prep,  dim3(256),        dim3(64),  0, stream, W, b, Wc, Wg, bsum);
    hipLaunchKernelGGL(hetconv_xconv, dim3(BATCH * 58), dim3(512), 0, stream, x, xb);
    hipLaunchKernelGGL(hetconv_main,  dim3(256),        dim3(512), 0, stream, xb, Wc, Wg, bsum, y);
}